// Round 1
// baseline (160.363 us; speedup 1.0000x reference)
//
#include <hip/hip_runtime.h>

// Conv4d as implicit GEMM on MFMA:
//   out[b][co][w][x][y][z] = sum_{kw,kx,ky,kz,ci} in[b][ci][w+kw][x+kx][y+ky][z+kz] * ker[off][ci][co]
// GEMM orientation: D[co][spatial] = W^T[co][ci] * IN[ci][spatial]
//   - A operand  = weights (co x ci), tiny, L2-resident, staged per offset (double-buffered)
//   - B operand  = input   (ci x z-line), staged per (kw,kx) as full 18x18x64 patch (reused by 9 offsets)
// Block = one (b,w,x): [64 co] x [256 spatial (16y x 16z)], 8 waves, wave wv owns y in {2wv, 2wv+1}.
// MFMA: v_mfma_f32_16x16x32_bf16. Per-lane operand k-map: k = 8*(lane>>4) + e (contiguous 8,
// one ds_read_b128 per fragment). C/D: col=lane&15 (=z), row=4*(lane>>4)+reg (=co)  [m89].
// LDS tiles XOR-swizzled at 8-element (16B) granule to break stride-128B bank conflicts.

typedef __attribute__((ext_vector_type(8))) short bf16x8;
typedef __attribute__((ext_vector_type(4))) float f32x4;

__device__ __forceinline__ unsigned short f2bf(float f) {
    unsigned int u = __float_as_uint(f);
    u += 0x7FFFu + ((u >> 16) & 1u);   // round-to-nearest-even
    return (unsigned short)(u >> 16);
}

__global__ __launch_bounds__(512, 2)
void conv4d_mfma(const float* __restrict__ in, const float* __restrict__ ker,
                 float* __restrict__ out) {
    // input patch: [rem = y'*18+z'] [ci (swizzled)]  : 18*18*64 bf16 = 41472 B
    __shared__ unsigned short T[18 * 18 * 64];
    // weights:     [co] [ci (swizzled)], double-buffered: 2*64*64 bf16 = 16384 B
    __shared__ unsigned short Wt[2][64 * 64];

    const int bx  = blockIdx.x;        // 512 = 2 * 16 * 16
    const int b   = bx >> 8;
    const int wsp = (bx >> 4) & 15;
    const int x   = bx & 15;

    const int t  = threadIdx.x;        // 0..511
    const int wv = t >> 6;             // wave 0..7
    const int l  = t & 63;
    const int lg = l >> 4;             // k-group 0..3
    const int ll = l & 15;             // row/col within 16-tile

    // in[b][ci][w'][x'][y'][z']: strides 6718464, 104976, 5832, 324, 18, 1
    const float* inb = in + (size_t)b * 6718464 + wsp * 5832 + x * 324;

    f32x4 acc[4][2];
#pragma unroll
    for (int i = 0; i < 4; ++i)
#pragma unroll
        for (int j = 0; j < 2; ++j)
            acc[i][j] = (f32x4){0.f, 0.f, 0.f, 0.f};

    // stage W[off=0] into buffer 0
#pragma unroll
    for (int f0 = 0; f0 < 4096; f0 += 512) {
        const int f = f0 + t;
        const int ci = f >> 6, co = f & 63;
        Wt[0][co * 64 + ((((ci >> 3) ^ (co & 7)) << 3) | (ci & 7))] = f2bf(ker[f]);
    }

    for (int off = 0; off < 81; ++off) {
        const int sub = off % 9;       // = ky*3 + kz

        if (sub == 0) {
            // stage the contiguous 18x18 (y',z') patch for all 64 ci at (kw,kx)
            const int kw = off / 27;
            const int kx = (off / 9) % 3;
            const float* p = inb + kw * 5832 + kx * 324;
            for (int f = t; f < 18 * 18 * 64; f += 512) {
                const int ci  = f / 324;
                const int rem = f - ci * 324;       // y'*18 + z', contiguous in global
                const int zp  = rem % 18;
                T[rem * 64 + ((((ci >> 3) ^ (zp & 7)) << 3) | (ci & 7))] =
                    f2bf(p[(size_t)ci * 104976 + rem]);
            }
        }
        if (off + 1 < 81) {
            // prefetch next offset's weights into the other buffer (no barrier needed:
            // its readers run next iteration, after the end-of-iter barrier)
            const float* p = ker + (off + 1) * 4096;
            unsigned short* wb = Wt[(off + 1) & 1];
#pragma unroll
            for (int f0 = 0; f0 < 4096; f0 += 512) {
                const int f = f0 + t;
                const int ci = f >> 6, co = f & 63;
                wb[co * 64 + ((((ci >> 3) ^ (co & 7)) << 3) | (ci & 7))] = f2bf(p[f]);
            }
        }
        if (sub == 0) __syncthreads();  // make T (and first W) visible

        const unsigned short* Wb = Wt[off & 1];
        const int ky = sub / 3;
        const int kz = sub - ky * 3;
        const int zp = ll + kz;         // z' = z + kz in [0,18)
        const int zs = zp & 7;

#pragma unroll
        for (int ks = 0; ks < 2; ++ks) {           // ci half: k = 32*ks + ...
            bf16x8 af[4];
#pragma unroll
            for (int rt = 0; rt < 4; ++rt) {       // co row-tiles
                const int co = rt * 16 + ll;
                af[rt] = *(const bf16x8*)&Wb[co * 64 + (((lg + 4 * ks) ^ (ll & 7)) << 3)];
            }
#pragma unroll
            for (int ct = 0; ct < 2; ++ct) {       // y col-tiles
                const int rem = (2 * wv + ct + ky) * 18 + zp;
                const bf16x8 bfr = *(const bf16x8*)&T[rem * 64 + (((lg + 4 * ks) ^ zs) << 3)];
#pragma unroll
                for (int rt = 0; rt < 4; ++rt)
                    acc[rt][ct] = __builtin_amdgcn_mfma_f32_16x16x32_bf16(
                        af[rt], bfr, acc[rt][ct], 0, 0, 0);
            }
        }
        __syncthreads();   // protect W-buffer reuse and T overwrite next iteration
    }

    // epilogue: D col = z (contiguous), rows = co at stride 65536
    float* ob = out + (size_t)b * 4194304 + wsp * 4096 + x * 256;
#pragma unroll
    for (int rt = 0; rt < 4; ++rt) {
        const int co0 = rt * 16 + 4 * lg;
#pragma unroll
        for (int ct = 0; ct < 2; ++ct) {
            const int base = (2 * wv + ct) * 16 + ll;
#pragma unroll
            for (int r = 0; r < 4; ++r)
                ob[(size_t)(co0 + r) * 65536 + base] = acc[rt][ct][r];
        }
    }
}

extern "C" void kernel_launch(void* const* d_in, const int* in_sizes, int n_in,
                              void* d_out, int out_size, void* d_ws, size_t ws_size,
                              hipStream_t stream) {
    const float* in  = (const float*)d_in[0];
    const float* ker = (const float*)d_in[1];
    conv4d_mfma<<<dim3(512), dim3(512), 0, stream>>>(in, ker, (float*)d_out);
}

// Round 2
// 111.568 us; speedup vs baseline: 1.4374x; 1.4374x over previous
//
#include <hip/hip_runtime.h>

// Conv4d implicit GEMM, v2.
// Pre-pass 1 (wprep): weights f32 -> bf16 in MFMA-fragment order:
//   Wg[off][rt 0..3][ks 0..1][lane 0..63][e 0..7],  co = rt*16 + (l&15), ci = ks*32 + (l>>4)*8 + e
// Pre-pass 2 (sprep): input f32 -> bf16 slabs, transposed + XOR-swizzled:
//   S[slab=(b,w',x')][rem=y'*18+z'][ci] at elem rem*64 + gi*8 + (ci&7), gi = (ci>>3) ^ (rem&7)
//   == the exact LDS image, so main-kernel staging is a linear global_load_lds copy.
// Main: block = (b,w,x), 256 thr (4 waves), wave tile 64co x (4y x 16z).
//   A-frags: direct global->VGPR dwordx4 (L2-resident, no LDS, no barrier).
//   B-frags: ds_read_b128 from T (2-way max bank aliasing = free).
//   Barriers only around T staging: 2 per 9-offset group.

typedef __attribute__((ext_vector_type(8))) short bf16x8;
typedef __attribute__((ext_vector_type(4))) float f32x4;
typedef __attribute__((ext_vector_type(8))) unsigned short ushort8;
typedef unsigned short u16;
typedef unsigned int u32;

#define S_OFF_BYTES 663552u          // Wg = 81*4096 u16 = 663552 B
#define WS_NEEDED   27537408u        // + 648 slabs * 41472 B

__device__ __forceinline__ u16 f2bf(float f) {
    u32 u = __float_as_uint(f);
    u += 0x7FFFu + ((u >> 16) & 1u);   // RNE
    return (u16)(u >> 16);
}

// ---------------- pre-pass 1: weights ----------------
__global__ __launch_bounds__(256) void wprep(const float* __restrict__ ker, u16* __restrict__ wg) {
    const int g = blockIdx.x * 256 + threadIdx.x;      // 0..41471
    const int l = g & 63, ks = (g >> 6) & 1, rt = (g >> 7) & 3, off = g >> 9;
    const int co  = rt * 16 + (l & 15);
    const int ci0 = ks * 32 + (l >> 4) * 8;
    const float* p = ker + (size_t)off * 4096 + co;
    ushort8 v;
#pragma unroll
    for (int e = 0; e < 8; ++e) v[e] = f2bf(p[(size_t)(ci0 + e) * 64]);
    *(ushort8*)(wg + (size_t)g * 8) = v;
}

// ---------------- pre-pass 2: input slabs ----------------
__global__ __launch_bounds__(256) void sprep(const float* __restrict__ in, u16* __restrict__ s) {
    __shared__ u16 L[64 * 330];                        // [ci][rem], pad 324->330 (2-way banks in phase 2)
    const int blk = blockIdx.x;                        // 648 = 2*18*18
    const int b = blk / 324, wx = blk - b * 324;
    const float* src = in + (size_t)b * 6718464 + (wx / 18) * 5832 + (wx % 18) * 324;
    const int t = threadIdx.x;
    for (int i = t; i < 5184; i += 256) {              // 64 ci * 81 float4
        const int ci = i / 81, j = i - ci * 81;
        float4 v = *(const float4*)(src + (size_t)ci * 104976 + j * 4);
        u32* q = (u32*)&L[ci * 330 + j * 4];
        q[0] = f2bf(v.x) | ((u32)f2bf(v.y) << 16);
        q[1] = f2bf(v.z) | ((u32)f2bf(v.w) << 16);
    }
    __syncthreads();
    u16* dst = s + (size_t)blk * 20736;
    for (int g = t; g < 2592; g += 256) {              // 324 rem * 8 granules
        const int rem = g >> 3, gi = g & 7;
        const int a = gi ^ (rem & 7);
        ushort8 v;
#pragma unroll
        for (int e = 0; e < 8; ++e) v[e] = L[(a * 8 + e) * 330 + rem];
        *(ushort8*)(dst + rem * 64 + gi * 8) = v;      // fully coalesced 16B/lane
    }
}

// ---------------- main ----------------
__global__ __launch_bounds__(256, 2)
void conv4d_main(const u16* __restrict__ wg, const u16* __restrict__ s, float* __restrict__ out) {
    __shared__ u16 T[324 * 64];                        // 41472 B, == S slab image

    const int bx = blockIdx.x;                         // 512 = 2*16*16
    const int b = bx >> 8, w = (bx >> 4) & 15, x = bx & 15;
    const int t = threadIdx.x, wv = t >> 6, l = t & 63;
    const int lg = l >> 4, ll = l & 15;

    f32x4 acc[4][4];
#pragma unroll
    for (int i = 0; i < 4; ++i)
#pragma unroll
        for (int j = 0; j < 4; ++j) acc[i][j] = (f32x4){0.f, 0.f, 0.f, 0.f};

    for (int kwx = 0; kwx < 9; ++kwx) {
        const int kw = kwx / 3, kx = kwx - kw * 3;
        const u16* src = s + ((size_t)b * 324 + (w + kw) * 18 + (x + kx)) * 20736;
        if (kwx) __syncthreads();                      // prior T reads complete
        for (int i = t; i < 2592; i += 256)            // 41472 B linear copy
            __builtin_amdgcn_global_load_lds(
                (const __attribute__((address_space(1))) u32*)(src + i * 8),
                (__attribute__((address_space(3))) u32*)&T[i * 8], 16, 0, 0);
        __syncthreads();                               // compiler drains vmcnt before barrier

#pragma unroll 3
        for (int sub = 0; sub < 9; ++sub) {            // barrier-free inner group
            const int ky = sub / 3, kz = sub - ky * 3;
            const u16* wo = wg + (size_t)(kwx * 9 + sub) * 4096;
#pragma unroll
            for (int ks = 0; ks < 2; ++ks) {
                bf16x8 a[4];
#pragma unroll
                for (int rt = 0; rt < 4; ++rt)         // global->VGPR, coalesced 16B/lane
                    a[rt] = *(const bf16x8*)(wo + ((size_t)(rt * 2 + ks) * 64 + l) * 8);
#pragma unroll
                for (int ct = 0; ct < 4; ++ct) {
                    const int rem = (wv * 4 + ct + ky) * 18 + ll + kz;
                    const bf16x8 bf = *(const bf16x8*)&T[rem * 64 + (((ks * 4 + lg) ^ (rem & 7)) << 3)];
#pragma unroll
                    for (int rt = 0; rt < 4; ++rt)
                        acc[rt][ct] = __builtin_amdgcn_mfma_f32_16x16x32_bf16(a[rt], bf, acc[rt][ct], 0, 0, 0);
                }
            }
        }
    }

    float* ob = out + (size_t)b * 4194304 + w * 4096 + x * 256;
#pragma unroll
    for (int rt = 0; rt < 4; ++rt) {
        const int co0 = rt * 16 + 4 * lg;
#pragma unroll
        for (int ct = 0; ct < 4; ++ct) {
            const int base = (wv * 4 + ct) * 16 + ll;
#pragma unroll
            for (int r = 0; r < 4; ++r)
                ob[(size_t)(co0 + r) * 65536 + base] = acc[rt][ct][r];
        }
    }
}

// ---------------- fallback (round-1 kernel, used if ws too small) ----------------
__global__ __launch_bounds__(512, 2)
void conv4d_mfma(const float* __restrict__ in, const float* __restrict__ ker,
                 float* __restrict__ out) {
    __shared__ unsigned short T[18 * 18 * 64];
    __shared__ unsigned short Wt[2][64 * 64];
    const int bx = blockIdx.x;
    const int b = bx >> 8, wsp = (bx >> 4) & 15, x = bx & 15;
    const int t = threadIdx.x, wv = t >> 6, l = t & 63;
    const int lg = l >> 4, ll = l & 15;
    const float* inb = in + (size_t)b * 6718464 + wsp * 5832 + x * 324;
    f32x4 acc[4][2];
#pragma unroll
    for (int i = 0; i < 4; ++i)
#pragma unroll
        for (int j = 0; j < 2; ++j) acc[i][j] = (f32x4){0.f, 0.f, 0.f, 0.f};
#pragma unroll
    for (int f0 = 0; f0 < 4096; f0 += 512) {
        const int f = f0 + t, ci = f >> 6, co = f & 63;
        Wt[0][co * 64 + ((((ci >> 3) ^ (co & 7)) << 3) | (ci & 7))] = f2bf(ker[f]);
    }
    for (int off = 0; off < 81; ++off) {
        const int sub = off % 9;
        if (sub == 0) {
            const int kw = off / 27, kx = (off / 9) % 3;
            const float* p = inb + kw * 5832 + kx * 324;
            for (int f = t; f < 18 * 18 * 64; f += 512) {
                const int ci = f / 324, rem = f - ci * 324, zp = rem % 18;
                T[rem * 64 + ((((ci >> 3) ^ (zp & 7)) << 3) | (ci & 7))] =
                    f2bf(p[(size_t)ci * 104976 + rem]);
            }
        }
        if (off + 1 < 81) {
            const float* p = ker + (off + 1) * 4096;
            unsigned short* wb = Wt[(off + 1) & 1];
#pragma unroll
            for (int f0 = 0; f0 < 4096; f0 += 512) {
                const int f = f0 + t, ci = f >> 6, co = f & 63;
                wb[co * 64 + ((((ci >> 3) ^ (co & 7)) << 3) | (ci & 7))] = f2bf(p[f]);
            }
        }
        if (sub == 0) __syncthreads();
        const unsigned short* Wb = Wt[off & 1];
        const int ky = sub / 3, kz = sub - ky * 3;
        const int zp = ll + kz, zs = zp & 7;
#pragma unroll
        for (int ks = 0; ks < 2; ++ks) {
            bf16x8 af[4];
#pragma unroll
            for (int rt = 0; rt < 4; ++rt)
                af[rt] = *(const bf16x8*)&Wb[(rt * 16 + ll) * 64 + (((lg + 4 * ks) ^ (ll & 7)) << 3)];
#pragma unroll
            for (int ct = 0; ct < 2; ++ct) {
                const int rem = (2 * wv + ct + ky) * 18 + zp;
                const bf16x8 bfr = *(const bf16x8*)&T[rem * 64 + (((lg + 4 * ks) ^ zs) << 3)];
#pragma unroll
                for (int rt = 0; rt < 4; ++rt)
                    acc[rt][ct] = __builtin_amdgcn_mfma_f32_16x16x32_bf16(af[rt], bfr, acc[rt][ct], 0, 0, 0);
            }
        }
        __syncthreads();
    }
    float* ob = out + (size_t)b * 4194304 + wsp * 4096 + x * 256;
#pragma unroll
    for (int rt = 0; rt < 4; ++rt) {
        const int co0 = rt * 16 + 4 * lg;
#pragma unroll
        for (int ct = 0; ct < 2; ++ct) {
            const int base = (2 * wv + ct) * 16 + ll;
#pragma unroll
            for (int r = 0; r < 4; ++r)
                ob[(size_t)(co0 + r) * 65536 + base] = acc[rt][ct][r];
        }
    }
}

extern "C" void kernel_launch(void* const* d_in, const int* in_sizes, int n_in,
                              void* d_out, int out_size, void* d_ws, size_t ws_size,
                              hipStream_t stream) {
    const float* in  = (const float*)d_in[0];
    const float* ker = (const float*)d_in[1];
    float* out = (float*)d_out;
    if (ws_size >= (size_t)WS_NEEDED) {
        u16* wg = (u16*)d_ws;
        u16* s  = (u16*)((char*)d_ws + S_OFF_BYTES);
        wprep<<<dim3(162), dim3(256), 0, stream>>>(ker, wg);
        sprep<<<dim3(648), dim3(256), 0, stream>>>(in, s);
        conv4d_main<<<dim3(512), dim3(256), 0, stream>>>(wg, s, out);
    } else {
        conv4d_mfma<<<dim3(512), dim3(512), 0, stream>>>(in, ker, out);
    }
}